// Round 11
// baseline (516.183 us; speedup 1.0000x reference)
//
#include <hip/hip_runtime.h>
#include <math.h>

typedef __attribute__((ext_vector_type(8))) __bf16 bf16x8;
typedef __attribute__((ext_vector_type(8))) unsigned short u16x8;
typedef __attribute__((ext_vector_type(4))) unsigned short u16x4;
typedef __attribute__((ext_vector_type(4))) float f32x4;

typedef unsigned int as1_u32 __attribute__((address_space(1)));
typedef unsigned int as3_u32 __attribute__((address_space(3)));

// ---------- helpers ----------
__device__ __forceinline__ float bf2f(unsigned short h){
  return __uint_as_float(((unsigned int)h) << 16);
}
__device__ __forceinline__ unsigned short f2bf(float f){
  unsigned int u = __float_as_uint(f);
  unsigned int r = (u + 0x7FFFu + ((u >> 16) & 1u)) >> 16;  // RNE
  return (unsigned short)r;
}

#if __has_builtin(__builtin_amdgcn_global_load_lds)
#define HAVE_GLOAD_LDS 1
__device__ __forceinline__ void gload16(const void* g, void* l){
  __builtin_amdgcn_global_load_lds((const as1_u32*)(unsigned long long)g,
                                   (as3_u32*)l, 16, 0, 0);
}
#else
#define HAVE_GLOAD_LDS 0
#endif

// ---------- prep_all: scatter+invp+ctr | transpose | conv(x4) | pe2b(x4) | bh32 ----------
// ranges: [0,49) scatter  [49,689) transpose  [689,2097) conv4  [2097,2225) pe2b4  [2225,2237) bh32
__global__ __launch_bounds__(256) void prep_all(
    const int* __restrict__ shuf, int* __restrict__ slot, int* __restrict__ invp,
    int* __restrict__ ctr,
    const float* __restrict__ Wpe, const float* __restrict__ outw,
    unsigned short* __restrict__ WpeT, unsigned short* __restrict__ outwT,
    const float* __restrict__ encW, const float* __restrict__ inW,
    const float* __restrict__ headW, unsigned short* __restrict__ wcat,
    const float* __restrict__ pos, const float* __restrict__ b_pe,
    const float* __restrict__ outb, const float* __restrict__ headb,
    unsigned short* __restrict__ pe2b, float* __restrict__ bh32)
{
  const int bid = blockIdx.x, t = threadIdx.x;
  __shared__ float tile[32][33];
  if (bid < 49){                                   // scatter: slot + inverse perm (+ctr reset)
    if (bid == 0 && t == 0) ctr[0] = 0;
    const int i = bid*256 + t;
    if (i < 64*196){
      const int b = i / 196, j = i % 196;
      const int p = shuf[b*196 + j];
      slot[b*196 + p] = (j < 147) ? j : -1;
      invp[b*196 + p] = j;
    }
  } else if (bid < 689){                           // transpose W_pe -> WpeT, out_w -> outwT
    int b2 = bid - 49;
    const float* src; unsigned short* dst; int R, C, bx, by;
    if (b2 < 384){ src = Wpe;  dst = WpeT;  R = 512; C = 768; bx = b2 % 24; by = b2 / 24; }
    else { b2 -= 384; src = outw; dst = outwT; R = 512; C = 512; bx = b2 % 16; by = b2 / 16; }
    const int tx = t & 31, ty = t >> 5;
    #pragma unroll
    for (int i = 0; i < 4; i++)
      tile[ty + i*8][tx] = src[(size_t)(by*32 + ty + i*8)*C + bx*32 + tx];
    __syncthreads();
    #pragma unroll
    for (int i = 0; i < 4; i++)
      dst[(size_t)(bx*32 + ty + i*8)*R + by*32 + tx] = f2bf(tile[tx][ty + i*8]);
  } else if (bid < 2097){                          // conv x4: encW|inW|headW -> bf16 wcat
    const int i = ((bid - 689)*256 + t) * 4;       // < 1441792; boundaries %4==0
    f32x4 v;
    if      (i <  262144) v = *(const f32x4*)(encW + i);
    else if (i < 1048576) v = *(const f32x4*)(inW + (i - 262144));
    else                  v = *(const f32x4*)(headW + (i - 1048576));
    u16x4 o = { f2bf(v[0]), f2bf(v[1]), f2bf(v[2]), f2bf(v[3]) };
    *(u16x4*)(wcat + i) = o;
  } else if (bid < 2225){                          // pe2b x4: rows 0..195 = pos+b_pe, 196..255 = 0
    const int i = ((bid - 2097)*256 + t) * 4;      // < 131072; 100352 %4==0, 512%4==0
    u16x4 o = {0, 0, 0, 0};
    if (i < 100352){
      const f32x4 pv = *(const f32x4*)(pos + i);
      const f32x4 bv = *(const f32x4*)(b_pe + (i & 511));
      o = u16x4{ f2bf(pv[0]+bv[0]), f2bf(pv[1]+bv[1]), f2bf(pv[2]+bv[2]), f2bf(pv[3]+bv[3]) };
    }
    *(u16x4*)(pe2b + i) = o;
  } else {                                         // bh32 = headW@outb + headb
    const int r = (bid - 2225)*64 + (t >> 2);      // 0..767
    const int q4 = t & 3;
    float a = 0.0f;
    const float* hw = headW + (size_t)r*512 + q4*128;
    const float* ob = outb + q4*128;
    for (int e = 0; e < 128; e++) a += hw[e] * ob[e];
    a += __shfl_down(a, 2, 4);
    a += __shfl_down(a, 1, 4);
    if (q4 == 0) bh32[r] = a + headb[r];
  }
}

// ---------- descriptor GEMM core (R5-proven structure) ----------
// tile 128x64, 4 waves (2x2; wave 64x32), BK=32, double-buffered LDS,
// prefetch-next-before-compute, ONE __syncthreads per K-step (compiler-scheduled waits).
struct GD {
  const unsigned short* A; const unsigned short* W; const float* aux;
  const int* tok; unsigned short* ob; float* of;
  int N, K, mode, blk0, nx;
};

__device__ __forceinline__ void gemm_core(const GD g, int local, unsigned char* smem){
  const int tn = (local % g.nx) * 64;
  const int tm = (local / g.nx) * 128;
  const int N = g.N, K = g.K;
  unsigned short* As = (unsigned short*)smem;                   // 2 * 128*32
  unsigned short* Bs = (unsigned short*)(smem + 2*128*32*2);    // 2 * 64*32
  const int t = threadIdx.x;
  const int wave = t >> 6, lane = t & 63;
  const int wr = (wave >> 1) * 64, wc = (wave & 1) * 32;
  const int lr = lane & 15, lg = lane >> 4;

  f32x4 acc[4][2] = {};
  const int nt = K >> 5;

#if HAVE_GLOAD_LDS
  const int srow = lane >> 2;
  const int scol = (lane & 3) * 8;
  const unsigned short* Ag = g.A + (size_t)(tm + wave*32 + srow) * K + scol;
  const unsigned short* Bg = g.W + (size_t)(tn + wave*16 + srow) * K + scol;
  const size_t rstepA = (size_t)16 * K;

  auto issue = [&](int tile_i, int slot_i){
    const int k0 = tile_i * 32;
    unsigned short* Al = As + slot_i*(128*32) + wave*(32*32);
    unsigned short* Bl = Bs + slot_i*(64*32)  + wave*(16*32);
    gload16(Ag + k0,          Al);
    gload16(Ag + k0 + rstepA, Al + 16*32);
    gload16(Bg + k0,          Bl);
  };

  issue(0, 0);
  __syncthreads();

  for (int tt = 0; tt < nt; ++tt){
    const int cur = tt & 1;
    if (tt + 1 < nt) issue(tt + 1, cur ^ 1);
    const unsigned short* Ab = As + cur*(128*32);
    const unsigned short* Bb = Bs + cur*(64*32);
    bf16x8 av[4], bv[2];
    #pragma unroll
    for (int mi = 0; mi < 4; mi++) av[mi] = *(const bf16x8*)&Ab[(wr + mi*16 + lr)*32 + lg*8];
    #pragma unroll
    for (int ni = 0; ni < 2; ni++) bv[ni] = *(const bf16x8*)&Bb[(wc + ni*16 + lr)*32 + lg*8];
    #pragma unroll
    for (int mi = 0; mi < 4; mi++)
      #pragma unroll
      for (int ni = 0; ni < 2; ni++)
        acc[mi][ni] = __builtin_amdgcn_mfma_f32_16x16x32_bf16(av[mi], bv[ni], acc[mi][ni], 0, 0, 0);
    __syncthreads();   // drains vmcnt(0): prefetched tile resident; LDS reads done
  }
#else
  unsigned short* As1 = (unsigned short*)smem;
  unsigned short* Bs1 = (unsigned short*)(smem + 128*32*2);
  const int r0 = t >> 2;
  const int c0 = (t & 3) * 8;
  for (int k0 = 0; k0 < K; k0 += 32){
    u16x8 ra0 = *(const u16x8*)(g.A + (size_t)(tm + r0) * K + k0 + c0);
    u16x8 rb0 = (r0 < 64) ? *(const u16x8*)(g.W + (size_t)(tn + r0) * K + k0 + c0) : u16x8{};
    __syncthreads();
    *(u16x8*)&As1[r0 * 32 + c0] = ra0;
    if (r0 < 64) *(u16x8*)&Bs1[r0 * 32 + c0] = rb0;
    __syncthreads();
    bf16x8 av[4], bv[2];
    #pragma unroll
    for (int mi = 0; mi < 4; mi++) av[mi] = *(const bf16x8*)&As1[(wr + mi*16 + lr)*32 + lg*8];
    #pragma unroll
    for (int ni = 0; ni < 2; ni++) bv[ni] = *(const bf16x8*)&Bs1[(wc + ni*16 + lr)*32 + lg*8];
    #pragma unroll
    for (int mi = 0; mi < 4; mi++)
      #pragma unroll
      for (int ni = 0; ni < 2; ni++)
        acc[mi][ni] = __builtin_amdgcn_mfma_f32_16x16x32_bf16(av[mi], bv[ni], acc[mi][ni], 0, 0, 0);
  }
#endif

  const int mode = g.mode;
  #pragma unroll
  for (int ni = 0; ni < 2; ni++){
    const int gcol = tn + wc + ni*16 + lr;
    const float bval = (mode == 0 || mode == 3) ? g.aux[gcol] : 0.0f;
    #pragma unroll
    for (int mi = 0; mi < 4; mi++){
      #pragma unroll
      for (int jj = 0; jj < 4; jj++){
        const int grow = tm + wr + mi*16 + lg*4 + jj;
        float v = acc[mi][ni][jj] + bval;
        if (mode == 1 || mode == 2) v += g.aux[(size_t)(g.tok[grow] & 255) * 512 + gcol];
        if (mode == 2){
          const float u = v;
          v = 0.5f * u * (1.0f + tanhf(0.7978845608f * (u + 0.044715f * u * u * u)));
        }
        if (mode == 3) g.of[(size_t)grow * N + gcol] = v;
        else           g.ob[(size_t)grow * N + gcol] = f2bf(v);
      }
    }
  }
}

// wrappers (24 KB LDS -> 6 blocks/CU)
__global__ __launch_bounds__(256) void gemm_one(GD g){
  __shared__ __align__(16) unsigned char smem[24576];
  gemm_core(g, blockIdx.x, smem);
}
__global__ __launch_bounds__(256) void gemm_two(GD a, GD b){
  __shared__ __align__(16) unsigned char smem[24576];
  GD g = (blockIdx.x >= b.blk0) ? b : a;
  gemm_core(g, blockIdx.x - g.blk0, smem);
}

// ---------- fold GEMMs + patchify-by-image, one launch ----------
// blocks [0,176): 5 fold GEMMs. blocks [176, 176+896): patchify, one per (b, gh).
__global__ __launch_bounds__(256) void fold_patch(GD g0, GD g1, GD g2, GD g3, GD g4,
    const float* __restrict__ x, const int* __restrict__ invp,
    unsigned short* __restrict__ maskA, unsigned short* __restrict__ unmaskA,
    int* __restrict__ tokcat)
{
  __shared__ __align__(16) unsigned char smem[24576];
  const int bid = blockIdx.x, t = threadIdx.x;
  if (bid < 176){
    GD g = g0;
    if (bid >= g1.blk0) g = g1;
    if (bid >= g2.blk0) g = g2;
    if (bid >= g3.blk0) g = g3;
    if (bid >= g4.blk0) g = g4;
    gemm_core(g, bid - g.blk0, smem);
    return;
  }
  // patchify: block per (b, gh); read 48 contiguous x rows, repack 14 patches
  const int blk = bid - 176;
  const int b = blk / 14, gh = blk % 14;
  unsigned short* ld = (unsigned short*)smem;   // [14][768] bf16
  for (int e = t; e < 2688; e += 256){          // 3*16*56 float4 loads
    const int w4 = e % 56, rest = e / 56;
    const int phi = rest & 15, c = rest >> 4;
    const f32x4 v4 = *(const f32x4*)(x + (size_t)b*150528 + c*50176
                                     + (size_t)(gh*16 + phi)*224 + w4*4);
    const int gw = w4 >> 2, part = w4 & 3;
    const int dbase = gw*768 + phi*48 + part*12 + c;
    ld[dbase]     = f2bf(v4[0]);
    ld[dbase + 3] = f2bf(v4[1]);
    ld[dbase + 6] = f2bf(v4[2]);
    ld[dbase + 9] = f2bf(v4[3]);
  }
  __syncthreads();
  for (int e = t; e < 1344; e += 256){          // 14 patches * 96 u16x8 stores
    const int gw = e / 96, elem8 = e % 96;
    const int p = gh*14 + gw;
    const int j = invp[b*196 + p];
    unsigned short* dst;
    int row;
    if (j < 147){ row = b*160 + j;        dst = maskA; }
    else        { row = b*64 + (j - 147); dst = unmaskA; }
    *(u16x8*)&dst[(size_t)row*768 + elem8*8] = *(const u16x8*)&ld[gw*768 + elem8*8];
    if (elem8 == 0) tokcat[(j < 147) ? (b*160 + j) : (10240 + b*64 + (j - 147))] = p;
  }
}

// ---------- MFMA attention: block per (b,h); pwt bf16; pa aliases qs ----------
__global__ __launch_bounds__(256) void attn_mfma(const unsigned short* __restrict__ qb,
                                                 const unsigned short* __restrict__ kv,
                                                 unsigned short* __restrict__ attnout)
{
  __shared__ __align__(16) unsigned char smem[72064];
  unsigned short* qs  = (unsigned short*)smem;            // [192][72], reused as pa
  unsigned short* ks  = (unsigned short*)(smem + 27648);  // [64][72]
  unsigned short* vsT = (unsigned short*)(smem + 36864);  // [64][72]
  unsigned short* pwt = (unsigned short*)(smem + 46080);  // [192][66] bf16 scores
  float* inv_ = (float*)(smem + 71424);                   // [160]
  const int b = blockIdx.x >> 3, h = blockIdx.x & 7;
  const int t = threadIdx.x;
  const int wave = t >> 6, lane = t & 63;
  const int wr = (wave >> 1) * 96, wc = (wave & 1) * 32;
  const int lr = lane & 15, lg = lane >> 4;

  for (int idx = t; idx < 192*8; idx += 256){
    const int i = idx >> 3, g = idx & 7;
    u16x8 v = {};
    if (i < 160) v = *(const u16x8*)(qb + (size_t)(b*160 + i)*512 + h*64 + g*8);
    *(u16x8*)&qs[i*72 + g*8] = v;
  }
  for (int idx = t; idx < 64*8; idx += 256){
    const int j = idx >> 3, g = idx & 7;
    const size_t base = (size_t)(b*64 + j)*1024 + h*64 + g*8;
    u16x8 k8 = *(const u16x8*)(kv + base);
    u16x8 v8 = *(const u16x8*)(kv + base + 512);
    *(u16x8*)&ks[j*72 + g*8] = k8;
    #pragma unroll
    for (int d = 0; d < 8; d++) vsT[(g*8 + d)*72 + j] = v8[d];
  }
  __syncthreads();

  // QK^T -> pwt (bf16, scaled)
  {
    f32x4 acc[6][2] = {};
    #pragma unroll
    for (int ksv = 0; ksv < 2; ksv++){
      const int kk = ksv*32;
      bf16x8 av[6], bv[2];
      #pragma unroll
      for (int mi = 0; mi < 6; mi++) av[mi] = *(const bf16x8*)&qs[(wr + mi*16 + lr)*72 + kk + lg*8];
      #pragma unroll
      for (int ni = 0; ni < 2; ni++) bv[ni] = *(const bf16x8*)&ks[(wc + ni*16 + lr)*72 + kk + lg*8];
      #pragma unroll
      for (int mi = 0; mi < 6; mi++)
        #pragma unroll
        for (int ni = 0; ni < 2; ni++)
          acc[mi][ni] = __builtin_amdgcn_mfma_f32_16x16x32_bf16(av[mi], bv[ni], acc[mi][ni], 0, 0, 0);
    }
    #pragma unroll
    for (int mi = 0; mi < 6; mi++)
      #pragma unroll
      for (int ni = 0; ni < 2; ni++)
        #pragma unroll
        for (int jj = 0; jj < 4; jj++)
          pwt[(wr + mi*16 + lg*4 + jj)*66 + wc + ni*16 + lr] = f2bf(acc[mi][ni][jj] * 0.125f);
  }
  __syncthreads();

  // softmax rows (mask j>=49); write pa (aliases qs — QK reads done)
  unsigned short* pa = qs;
  if (t < 147){
    float sc[49];
    float m = -1e30f;
    #pragma unroll 7
    for (int j = 0; j < 49; j++){ sc[j] = bf2f(pwt[t*66 + j]); m = fmaxf(m, sc[j]); }
    float sum = 0.0f;
    for (int j = 0; j < 49; j++){
      const float e = __expf(sc[j] - m);
      sum += e;
      pa[t*72 + j] = f2bf(e);
    }
    inv_[t] = 1.0f / sum;
    for (int j = 49; j < 64; j++) pa[t*72 + j] = 0;
  } else if (t < 192){
    for (int j = 0; j < 64; j++) pa[t*72 + j] = 0;
    if (t < 160) inv_[t] = 0.0f;
  }
  __syncthreads();

  // PV
  {
    f32x4 acc[6][2] = {};
    #pragma unroll
    for (int ksv = 0; ksv < 2; ksv++){
      const int kk = ksv*32;
      bf16x8 av[6], bv[2];
      #pragma unroll
      for (int mi = 0; mi < 6; mi++) av[mi] = *(const bf16x8*)&pa[(wr + mi*16 + lr)*72 + kk + lg*8];
      #pragma unroll
      for (int ni = 0; ni < 2; ni++) bv[ni] = *(const bf16x8*)&vsT[(wc + ni*16 + lr)*72 + kk + lg*8];
      #pragma unroll
      for (int mi = 0; mi < 6; mi++)
        #pragma unroll
        for (int ni = 0; ni < 2; ni++)
          acc[mi][ni] = __builtin_amdgcn_mfma_f32_16x16x32_bf16(av[mi], bv[ni], acc[mi][ni], 0, 0, 0);
    }
    #pragma unroll
    for (int mi = 0; mi < 6; mi++)
      #pragma unroll
      for (int ni = 0; ni < 2; ni++)
        #pragma unroll
        for (int jj = 0; jj < 4; jj++){
          const int grow = wr + mi*16 + lg*4 + jj;
          if (grow < 160){
            const float v = acc[mi][ni][jj] * inv_[grow];
            attnout[(size_t)(b*160 + grow)*512 + h*64 + wc + ni*16 + lr] = f2bf(v);
          }
        }
  }
}

// ---------- final: three images + |err|; row-major (R8); fused mse via last-block ----------
__global__ __launch_bounds__(256) void finalize_k(const float* __restrict__ x, const int* __restrict__ slot,
                           const unsigned short* __restrict__ predb, const float* __restrict__ noise,
                           float* __restrict__ out, float* __restrict__ partial, int* __restrict__ ctr)
{
  const int i4 = blockIdx.x * 256 + threadIdx.x;
  const int idx = i4 * 4;
  const int w = idx % 224;
  const int h = (idx / 224) % 224;
  const int c = (idx / 50176) % 3;
  const int b = idx / 150528;
  const f32x4 xv = *(const f32x4*)(x + idx);
  const int p = (h >> 4) * 14 + (w >> 4);
  const int s = slot[b*196 + p];
  f32x4 rec = xv, noi = xv, mim = xv;
  float a = 0.0f;
  if (s >= 0){
    const int d = (h & 15)*48 + (w & 15)*3 + c;
    const size_t pb = (size_t)(b*160 + s)*768 + d;
    const size_t nb = (size_t)(b*147 + s)*768 + d;
    rec = f32x4{bf2f(predb[pb]), bf2f(predb[pb+3]), bf2f(predb[pb+6]), bf2f(predb[pb+9])};
    noi = f32x4{noise[nb], noise[nb+3], noise[nb+6], noise[nb+9]};
    mim = f32x4{1.0f, 1.0f, 1.0f, 1.0f};
    a = fabsf(rec[0] - xv[0]) + fabsf(rec[1] - xv[1]) + fabsf(rec[2] - xv[2]) + fabsf(rec[3] - xv[3]);
  }
  *(f32x4*)(out + idx) = rec;
  *(f32x4*)(out + 9633792 + idx) = noi;
  // mask_image starts at odd offset 19267585: shifted aligned store
  float prevm = __shfl_up(mim[3], 1);
  if ((threadIdx.x & 63) == 0 && idx > 0){
    const int pidx = idx - 1;
    const int pw2 = pidx % 224, ph2 = (pidx / 224) % 224;
    const int pb2 = pidx / 150528;
    const int pp = (ph2 >> 4) * 14 + (pw2 >> 4);
    prevm = (slot[pb2*196 + pp] >= 0) ? 1.0f : x[pidx];
  }
  *(f32x4*)(out + 19267584 + idx) = f32x4{prevm, mim[0], mim[1], mim[2]};
  if (i4 == 2408447) out[28901376] = mim[3];   // tail pixel
  // block reduce -> partial
  #pragma unroll
  for (int o = 32; o > 0; o >>= 1) a += __shfl_down(a, o);
  __shared__ float wsum[4];
  __shared__ int isLast;
  if ((threadIdx.x & 63) == 0) wsum[threadIdx.x >> 6] = a;
  __syncthreads();
  if (threadIdx.x == 0){
    partial[blockIdx.x] = wsum[0] + wsum[1] + wsum[2] + wsum[3];
    __threadfence();
    isLast = (atomicAdd(ctr, 1) == 9407);
  }
  __syncthreads();
  if (isLast){
    __threadfence();
    float s2 = 0.0f;
    for (int i = threadIdx.x; i < 9408; i += 256) s2 += partial[i];   // fixed order -> deterministic
    #pragma unroll
    for (int o = 32; o > 0; o >>= 1) s2 += __shfl_down(s2, o);
    if ((threadIdx.x & 63) == 0) wsum[threadIdx.x >> 6] = s2;
    __syncthreads();
    if (threadIdx.x == 0)
      out[19267584] = (wsum[0] + wsum[1] + wsum[2] + wsum[3]) * (1.0f / 7225344.0f);
  }
}

// ---------- launch ----------
extern "C" void kernel_launch(void* const* d_in, const int* in_sizes, int n_in,
                              void* d_out, int out_size, void* d_ws, size_t ws_size,
                              hipStream_t stream)
{
  const float* x     = (const float*)d_in[0];
  const int*   shuf  = (const int*)d_in[1];
  const float* W_pe  = (const float*)d_in[2];
  const float* b_pe  = (const float*)d_in[3];
  const float* pos   = (const float*)d_in[4];
  const float* encW  = (const float*)d_in[5];
  const float* encB  = (const float*)d_in[6];
  const float* inW   = (const float*)d_in[7];
  const float* inB   = (const float*)d_in[8];
  const float* outW  = (const float*)d_in[9];
  const float* outB  = (const float*)d_in[10];
  const float* headW = (const float*)d_in[11];
  const float* headB = (const float*)d_in[12];
  const float* noise = (const float*)d_in[13];
  float* out = (float*)d_out;

  char* ws = (char*)d_ws;
  size_t cur = 0;
  auto alloc = [&](size_t bytes){ size_t o = cur; cur += (bytes + 255) & ~(size_t)255; return o; };

  int*   slot    = (int*)(ws + alloc(64*196*4));
  int*   invp    = (int*)(ws + alloc(64*196*4));
  int*   tokcat  = (int*)(ws + alloc(14336*4));
  int*   ctr     = (int*)(ws + alloc(256));
  float* partial = (float*)(ws + alloc(9408*4));
  unsigned short* wcat    = (unsigned short*)(ws + alloc((size_t)1441792*2));
  unsigned short* encw_b  = wcat;
  unsigned short* inw_b   = wcat +  262144;   // [Wq;Wk;Wv]
  unsigned short* headw_b = wcat + 1048576;   // [768][512]
  unsigned short* WpeT  = (unsigned short*)(ws + alloc((size_t)393216*2));  // [768][512]
  unsigned short* outwT = (unsigned short*)(ws + alloc((size_t)262144*2));  // [512][512]
  unsigned short* Wqpe  = (unsigned short*)(ws + alloc((size_t)393216*2));  // [512][768]
  unsigned short* Wepe  = (unsigned short*)(ws + alloc((size_t)393216*2));  // [512][768]
  unsigned short* Whp   = (unsigned short*)(ws + alloc((size_t)393216*2));  // [768][512]
  unsigned short* pe2b  = (unsigned short*)(ws + alloc((size_t)131072*2));  // [256][512]
  float* peq  = (float*)(ws + alloc((size_t)131072*4));
  float* pee  = (float*)(ws + alloc((size_t)131072*4));
  float* bh32 = (float*)(ws + alloc(768*4));
  unsigned short* maskA   = (unsigned short*)(ws + alloc((size_t)7864320*2));   // [10240][768]
  unsigned short* unmaskA = (unsigned short*)(ws + alloc((size_t)3145728*2));   // [4096][768]
  unsigned short* attnout = (unsigned short*)(ws + alloc((size_t)5242880*2));   // [10240][512]
  unsigned short* predb   = (unsigned short*)(ws + alloc((size_t)7864320*2));   // [10240][768]
  unsigned short* enc   = (unsigned short*)(ws + alloc((size_t)2097152*2));
  unsigned short* qb    = (unsigned short*)(ws + alloc((size_t)5242880*2));
  unsigned short* kvb   = (unsigned short*)(ws + alloc((size_t)4194304*2));

  prep_all<<<2237, 256, 0, stream>>>(shuf, slot, invp, ctr, W_pe, outW, WpeT, outwT,
                                     encW, inW, headW, wcat,
                                     pos, b_pe, outB, headB, pe2b, bh32);

  // fold GEMMs + patchify (one launch, 176 + 896 blocks)
  {
    GD t1 = { inw_b,  WpeT,   nullptr, nullptr, Wqpe,   nullptr, 768, 512, 4,   0, 12 };
    GD t2 = { encw_b, WpeT,   nullptr, nullptr, Wepe,   nullptr, 768, 512, 4,  48, 12 };
    GD t3 = { headw_b,outwT,  nullptr, nullptr, Whp,    nullptr, 512, 512, 4,  96,  8 };
    GD t4 = { pe2b,   inw_b,  inB,     nullptr, nullptr, peq,    512, 512, 3, 144,  8 };
    GD t5 = { pe2b,   encw_b, encB,    nullptr, nullptr, pee,    512, 512, 3, 160,  8 };
    fold_patch<<<1072, 256, 0, stream>>>(t1, t2, t3, t4, t5, x, invp, maskA, unmaskA, tokcat);
  }
  // q + enc (one launch, 896 blocks)
  {
    GD q  = { maskA,   Wqpe, peq, tokcat,         qb,  nullptr, 512, 768, 1,   0, 8 };
    GD en = { unmaskA, Wepe, pee, tokcat + 10240, enc, nullptr, 512, 768, 2, 640, 8 };
    gemm_two<<<896, 256, 0, stream>>>(q, en);
  }
  // kv = enc @ [Wk;Wv]^T + [bk;bv]
  {
    GD kv = { enc, inw_b + (size_t)512*512, inB + 512, nullptr, kvb, nullptr, 1024, 512, 0, 0, 16 };
    gemm_one<<<512, 256, 0, stream>>>(kv);
  }
  attn_mfma<<<512, 256, 0, stream>>>(qb, kvb, attnout);
  // pred = attn_raw @ Whp^T + bh
  {
    GD pr = { attnout, Whp, bh32, nullptr, predb, nullptr, 768, 512, 0, 0, 12 };
    gemm_one<<<960, 256, 0, stream>>>(pr);
  }

  finalize_k<<<9408, 256, 0, stream>>>(x, slot, predb, noise, out, partial, ctr);
}

// Round 12
// 180.517 us; speedup vs baseline: 2.8595x; 2.8595x over previous
//
#include <hip/hip_runtime.h>
#include <math.h>

typedef __attribute__((ext_vector_type(8))) __bf16 bf16x8;
typedef __attribute__((ext_vector_type(8))) unsigned short u16x8;
typedef __attribute__((ext_vector_type(4))) unsigned short u16x4;
typedef __attribute__((ext_vector_type(4))) float f32x4;

typedef unsigned int as1_u32 __attribute__((address_space(1)));
typedef unsigned int as3_u32 __attribute__((address_space(3)));

// ---------- helpers ----------
__device__ __forceinline__ float bf2f(unsigned short h){
  return __uint_as_float(((unsigned int)h) << 16);
}
__device__ __forceinline__ unsigned short f2bf(float f){
  unsigned int u = __float_as_uint(f);
  unsigned int r = (u + 0x7FFFu + ((u >> 16) & 1u)) >> 16;  // RNE
  return (unsigned short)r;
}

#if __has_builtin(__builtin_amdgcn_global_load_lds)
#define HAVE_GLOAD_LDS 1
__device__ __forceinline__ void gload16(const void* g, void* l){
  __builtin_amdgcn_global_load_lds((const as1_u32*)(unsigned long long)g,
                                   (as3_u32*)l, 16, 0, 0);
}
#else
#define HAVE_GLOAD_LDS 0
#endif

// ---------- prep_all: scatter+invp | transpose | conv(x4) | pe2b(x4) | bh32 ----------
// ranges: [0,49) scatter  [49,689) transpose  [689,2097) conv4  [2097,2225) pe2b4  [2225,2237) bh32
__global__ __launch_bounds__(256) void prep_all(
    const int* __restrict__ shuf, int* __restrict__ slot, int* __restrict__ invp,
    const float* __restrict__ Wpe, const float* __restrict__ outw,
    unsigned short* __restrict__ WpeT, unsigned short* __restrict__ outwT,
    const float* __restrict__ encW, const float* __restrict__ inW,
    const float* __restrict__ headW, unsigned short* __restrict__ wcat,
    const float* __restrict__ pos, const float* __restrict__ b_pe,
    const float* __restrict__ outb, const float* __restrict__ headb,
    unsigned short* __restrict__ pe2b, float* __restrict__ bh32)
{
  const int bid = blockIdx.x, t = threadIdx.x;
  __shared__ float tile[32][33];
  if (bid < 49){                                   // scatter: slot + inverse perm
    const int i = bid*256 + t;
    if (i < 64*196){
      const int b = i / 196, j = i % 196;
      const int p = shuf[b*196 + j];
      slot[b*196 + p] = (j < 147) ? j : -1;
      invp[b*196 + p] = j;
    }
  } else if (bid < 689){                           // transpose W_pe -> WpeT, out_w -> outwT
    int b2 = bid - 49;
    const float* src; unsigned short* dst; int R, C, bx, by;
    if (b2 < 384){ src = Wpe;  dst = WpeT;  R = 512; C = 768; bx = b2 % 24; by = b2 / 24; }
    else { b2 -= 384; src = outw; dst = outwT; R = 512; C = 512; bx = b2 % 16; by = b2 / 16; }
    const int tx = t & 31, ty = t >> 5;
    #pragma unroll
    for (int i = 0; i < 4; i++)
      tile[ty + i*8][tx] = src[(size_t)(by*32 + ty + i*8)*C + bx*32 + tx];
    __syncthreads();
    #pragma unroll
    for (int i = 0; i < 4; i++)
      dst[(size_t)(bx*32 + ty + i*8)*R + by*32 + tx] = f2bf(tile[tx][ty + i*8]);
  } else if (bid < 2097){                          // conv x4: encW|inW|headW -> bf16 wcat
    const int i = ((bid - 689)*256 + t) * 4;       // < 1441792; boundaries %4==0
    f32x4 v;
    if      (i <  262144) v = *(const f32x4*)(encW + i);
    else if (i < 1048576) v = *(const f32x4*)(inW + (i - 262144));
    else                  v = *(const f32x4*)(headW + (i - 1048576));
    u16x4 o = { f2bf(v[0]), f2bf(v[1]), f2bf(v[2]), f2bf(v[3]) };
    *(u16x4*)(wcat + i) = o;
  } else if (bid < 2225){                          // pe2b x4: rows 0..195 = pos+b_pe, 196..255 = 0
    const int i = ((bid - 2097)*256 + t) * 4;      // < 131072; 100352 %4==0, 512%4==0
    u16x4 o = {0, 0, 0, 0};
    if (i < 100352){
      const f32x4 pv = *(const f32x4*)(pos + i);
      const f32x4 bv = *(const f32x4*)(b_pe + (i & 511));
      o = u16x4{ f2bf(pv[0]+bv[0]), f2bf(pv[1]+bv[1]), f2bf(pv[2]+bv[2]), f2bf(pv[3]+bv[3]) };
    }
    *(u16x4*)(pe2b + i) = o;
  } else {                                         // bh32 = headW@outb + headb
    const int r = (bid - 2225)*64 + (t >> 2);      // 0..767
    const int q4 = t & 3;
    float a = 0.0f;
    const float* hw = headW + (size_t)r*512 + q4*128;
    const float* ob = outb + q4*128;
    for (int e = 0; e < 128; e++) a += hw[e] * ob[e];
    a += __shfl_down(a, 2, 4);
    a += __shfl_down(a, 1, 4);
    if (q4 == 0) bh32[r] = a + headb[r];
  }
}

// ---------- descriptor GEMM core (R5-proven structure) ----------
// tile 128x64, 4 waves (2x2; wave 64x32), BK=32, double-buffered LDS,
// prefetch-next-before-compute, ONE __syncthreads per K-step (compiler-scheduled waits).
struct GD {
  const unsigned short* A; const unsigned short* W; const float* aux;
  const int* tok; unsigned short* ob; float* of;
  int N, K, mode, blk0, nx;
};

__device__ __forceinline__ void gemm_core(const GD g, int local, unsigned char* smem){
  const int tn = (local % g.nx) * 64;
  const int tm = (local / g.nx) * 128;
  const int N = g.N, K = g.K;
  unsigned short* As = (unsigned short*)smem;                   // 2 * 128*32
  unsigned short* Bs = (unsigned short*)(smem + 2*128*32*2);    // 2 * 64*32
  const int t = threadIdx.x;
  const int wave = t >> 6, lane = t & 63;
  const int wr = (wave >> 1) * 64, wc = (wave & 1) * 32;
  const int lr = lane & 15, lg = lane >> 4;

  f32x4 acc[4][2] = {};
  const int nt = K >> 5;

#if HAVE_GLOAD_LDS
  const int srow = lane >> 2;
  const int scol = (lane & 3) * 8;
  const unsigned short* Ag = g.A + (size_t)(tm + wave*32 + srow) * K + scol;
  const unsigned short* Bg = g.W + (size_t)(tn + wave*16 + srow) * K + scol;
  const size_t rstepA = (size_t)16 * K;

  auto issue = [&](int tile_i, int slot_i){
    const int k0 = tile_i * 32;
    unsigned short* Al = As + slot_i*(128*32) + wave*(32*32);
    unsigned short* Bl = Bs + slot_i*(64*32)  + wave*(16*32);
    gload16(Ag + k0,          Al);
    gload16(Ag + k0 + rstepA, Al + 16*32);
    gload16(Bg + k0,          Bl);
  };

  issue(0, 0);
  __syncthreads();

  for (int tt = 0; tt < nt; ++tt){
    const int cur = tt & 1;
    if (tt + 1 < nt) issue(tt + 1, cur ^ 1);
    const unsigned short* Ab = As + cur*(128*32);
    const unsigned short* Bb = Bs + cur*(64*32);
    bf16x8 av[4], bv[2];
    #pragma unroll
    for (int mi = 0; mi < 4; mi++) av[mi] = *(const bf16x8*)&Ab[(wr + mi*16 + lr)*32 + lg*8];
    #pragma unroll
    for (int ni = 0; ni < 2; ni++) bv[ni] = *(const bf16x8*)&Bb[(wc + ni*16 + lr)*32 + lg*8];
    #pragma unroll
    for (int mi = 0; mi < 4; mi++)
      #pragma unroll
      for (int ni = 0; ni < 2; ni++)
        acc[mi][ni] = __builtin_amdgcn_mfma_f32_16x16x32_bf16(av[mi], bv[ni], acc[mi][ni], 0, 0, 0);
    __syncthreads();   // drains vmcnt(0): prefetched tile resident; LDS reads done
  }
#else
  unsigned short* As1 = (unsigned short*)smem;
  unsigned short* Bs1 = (unsigned short*)(smem + 128*32*2);
  const int r0 = t >> 2;
  const int c0 = (t & 3) * 8;
  for (int k0 = 0; k0 < K; k0 += 32){
    u16x8 ra0 = *(const u16x8*)(g.A + (size_t)(tm + r0) * K + k0 + c0);
    u16x8 rb0 = (r0 < 64) ? *(const u16x8*)(g.W + (size_t)(tn + r0) * K + k0 + c0) : u16x8{};
    __syncthreads();
    *(u16x8*)&As1[r0 * 32 + c0] = ra0;
    if (r0 < 64) *(u16x8*)&Bs1[r0 * 32 + c0] = rb0;
    __syncthreads();
    bf16x8 av[4], bv[2];
    #pragma unroll
    for (int mi = 0; mi < 4; mi++) av[mi] = *(const bf16x8*)&As1[(wr + mi*16 + lr)*32 + lg*8];
    #pragma unroll
    for (int ni = 0; ni < 2; ni++) bv[ni] = *(const bf16x8*)&Bs1[(wc + ni*16 + lr)*32 + lg*8];
    #pragma unroll
    for (int mi = 0; mi < 4; mi++)
      #pragma unroll
      for (int ni = 0; ni < 2; ni++)
        acc[mi][ni] = __builtin_amdgcn_mfma_f32_16x16x32_bf16(av[mi], bv[ni], acc[mi][ni], 0, 0, 0);
  }
#endif

  const int mode = g.mode;
  #pragma unroll
  for (int ni = 0; ni < 2; ni++){
    const int gcol = tn + wc + ni*16 + lr;
    const float bval = (mode == 0 || mode == 3) ? g.aux[gcol] : 0.0f;
    #pragma unroll
    for (int mi = 0; mi < 4; mi++){
      #pragma unroll
      for (int jj = 0; jj < 4; jj++){
        const int grow = tm + wr + mi*16 + lg*4 + jj;
        float v = acc[mi][ni][jj] + bval;
        if (mode == 1 || mode == 2) v += g.aux[(size_t)(g.tok[grow] & 255) * 512 + gcol];
        if (mode == 2){
          const float u = v;
          v = 0.5f * u * (1.0f + tanhf(0.7978845608f * (u + 0.044715f * u * u * u)));
        }
        if (mode == 3) g.of[(size_t)grow * N + gcol] = v;
        else           g.ob[(size_t)grow * N + gcol] = f2bf(v);
      }
    }
  }
}

// wrappers (24 KB LDS -> 6 blocks/CU)
__global__ __launch_bounds__(256) void gemm_one(GD g){
  __shared__ __align__(16) unsigned char smem[24576];
  gemm_core(g, blockIdx.x, smem);
}
__global__ __launch_bounds__(256) void gemm_two(GD a, GD b){
  __shared__ __align__(16) unsigned char smem[24576];
  GD g = (blockIdx.x >= b.blk0) ? b : a;
  gemm_core(g, blockIdx.x - g.blk0, smem);
}

// ---------- fold GEMMs + patchify-by-image, one launch ----------
// blocks [0,176): 5 fold GEMMs. blocks [176, 176+896): patchify, one per (b, gh).
__global__ __launch_bounds__(256) void fold_patch(GD g0, GD g1, GD g2, GD g3, GD g4,
    const float* __restrict__ x, const int* __restrict__ invp,
    unsigned short* __restrict__ maskA, unsigned short* __restrict__ unmaskA,
    int* __restrict__ tokcat)
{
  __shared__ __align__(16) unsigned char smem[24576];
  const int bid = blockIdx.x, t = threadIdx.x;
  if (bid < 176){
    GD g = g0;
    if (bid >= g1.blk0) g = g1;
    if (bid >= g2.blk0) g = g2;
    if (bid >= g3.blk0) g = g3;
    if (bid >= g4.blk0) g = g4;
    gemm_core(g, bid - g.blk0, smem);
    return;
  }
  // patchify: block per (b, gh); read 48 contiguous x rows, repack 14 patches
  const int blk = bid - 176;
  const int b = blk / 14, gh = blk % 14;
  unsigned short* ld = (unsigned short*)smem;   // [14][768] bf16
  for (int e = t; e < 2688; e += 256){          // 3*16*56 float4 loads
    const int w4 = e % 56, rest = e / 56;
    const int phi = rest & 15, c = rest >> 4;
    const f32x4 v4 = *(const f32x4*)(x + (size_t)b*150528 + c*50176
                                     + (size_t)(gh*16 + phi)*224 + w4*4);
    const int gw = w4 >> 2, part = w4 & 3;
    const int dbase = gw*768 + phi*48 + part*12 + c;
    ld[dbase]     = f2bf(v4[0]);
    ld[dbase + 3] = f2bf(v4[1]);
    ld[dbase + 6] = f2bf(v4[2]);
    ld[dbase + 9] = f2bf(v4[3]);
  }
  __syncthreads();
  for (int e = t; e < 1344; e += 256){          // 14 patches * 96 u16x8 stores
    const int gw = e / 96, elem8 = e % 96;
    const int p = gh*14 + gw;
    const int j = invp[b*196 + p];
    unsigned short* dst;
    int row;
    if (j < 147){ row = b*160 + j;        dst = maskA; }
    else        { row = b*64 + (j - 147); dst = unmaskA; }
    *(u16x8*)&dst[(size_t)row*768 + elem8*8] = *(const u16x8*)&ld[gw*768 + elem8*8];
    if (elem8 == 0) tokcat[(j < 147) ? (b*160 + j) : (10240 + b*64 + (j - 147))] = p;
  }
}

// ---------- MFMA attention: block per (b,h); pwt bf16; pa aliases qs ----------
__global__ __launch_bounds__(256) void attn_mfma(const unsigned short* __restrict__ qb,
                                                 const unsigned short* __restrict__ kv,
                                                 unsigned short* __restrict__ attnout)
{
  __shared__ __align__(16) unsigned char smem[72064];
  unsigned short* qs  = (unsigned short*)smem;            // [192][72], reused as pa
  unsigned short* ks  = (unsigned short*)(smem + 27648);  // [64][72]
  unsigned short* vsT = (unsigned short*)(smem + 36864);  // [64][72]
  unsigned short* pwt = (unsigned short*)(smem + 46080);  // [192][66] bf16 scores
  float* inv_ = (float*)(smem + 71424);                   // [160]
  const int b = blockIdx.x >> 3, h = blockIdx.x & 7;
  const int t = threadIdx.x;
  const int wave = t >> 6, lane = t & 63;
  const int wr = (wave >> 1) * 96, wc = (wave & 1) * 32;
  const int lr = lane & 15, lg = lane >> 4;

  for (int idx = t; idx < 192*8; idx += 256){
    const int i = idx >> 3, g = idx & 7;
    u16x8 v = {};
    if (i < 160) v = *(const u16x8*)(qb + (size_t)(b*160 + i)*512 + h*64 + g*8);
    *(u16x8*)&qs[i*72 + g*8] = v;
  }
  for (int idx = t; idx < 64*8; idx += 256){
    const int j = idx >> 3, g = idx & 7;
    const size_t base = (size_t)(b*64 + j)*1024 + h*64 + g*8;
    u16x8 k8 = *(const u16x8*)(kv + base);
    u16x8 v8 = *(const u16x8*)(kv + base + 512);
    *(u16x8*)&ks[j*72 + g*8] = k8;
    #pragma unroll
    for (int d = 0; d < 8; d++) vsT[(g*8 + d)*72 + j] = v8[d];
  }
  __syncthreads();

  // QK^T -> pwt (bf16, scaled)
  {
    f32x4 acc[6][2] = {};
    #pragma unroll
    for (int ksv = 0; ksv < 2; ksv++){
      const int kk = ksv*32;
      bf16x8 av[6], bv[2];
      #pragma unroll
      for (int mi = 0; mi < 6; mi++) av[mi] = *(const bf16x8*)&qs[(wr + mi*16 + lr)*72 + kk + lg*8];
      #pragma unroll
      for (int ni = 0; ni < 2; ni++) bv[ni] = *(const bf16x8*)&ks[(wc + ni*16 + lr)*72 + kk + lg*8];
      #pragma unroll
      for (int mi = 0; mi < 6; mi++)
        #pragma unroll
        for (int ni = 0; ni < 2; ni++)
          acc[mi][ni] = __builtin_amdgcn_mfma_f32_16x16x32_bf16(av[mi], bv[ni], acc[mi][ni], 0, 0, 0);
    }
    #pragma unroll
    for (int mi = 0; mi < 6; mi++)
      #pragma unroll
      for (int ni = 0; ni < 2; ni++)
        #pragma unroll
        for (int jj = 0; jj < 4; jj++)
          pwt[(wr + mi*16 + lg*4 + jj)*66 + wc + ni*16 + lr] = f2bf(acc[mi][ni][jj] * 0.125f);
  }
  __syncthreads();

  // softmax rows (mask j>=49); write pa (aliases qs — QK reads done)
  unsigned short* pa = qs;
  if (t < 147){
    float sc[49];
    float m = -1e30f;
    #pragma unroll 7
    for (int j = 0; j < 49; j++){ sc[j] = bf2f(pwt[t*66 + j]); m = fmaxf(m, sc[j]); }
    float sum = 0.0f;
    for (int j = 0; j < 49; j++){
      const float e = __expf(sc[j] - m);
      sum += e;
      pa[t*72 + j] = f2bf(e);
    }
    inv_[t] = 1.0f / sum;
    for (int j = 49; j < 64; j++) pa[t*72 + j] = 0;
  } else if (t < 192){
    for (int j = 0; j < 64; j++) pa[t*72 + j] = 0;
    if (t < 160) inv_[t] = 0.0f;
  }
  __syncthreads();

  // PV
  {
    f32x4 acc[6][2] = {};
    #pragma unroll
    for (int ksv = 0; ksv < 2; ksv++){
      const int kk = ksv*32;
      bf16x8 av[6], bv[2];
      #pragma unroll
      for (int mi = 0; mi < 6; mi++) av[mi] = *(const bf16x8*)&pa[(wr + mi*16 + lr)*72 + kk + lg*8];
      #pragma unroll
      for (int ni = 0; ni < 2; ni++) bv[ni] = *(const bf16x8*)&vsT[(wc + ni*16 + lr)*72 + kk + lg*8];
      #pragma unroll
      for (int mi = 0; mi < 6; mi++)
        #pragma unroll
        for (int ni = 0; ni < 2; ni++)
          acc[mi][ni] = __builtin_amdgcn_mfma_f32_16x16x32_bf16(av[mi], bv[ni], acc[mi][ni], 0, 0, 0);
    }
    #pragma unroll
    for (int mi = 0; mi < 6; mi++)
      #pragma unroll
      for (int ni = 0; ni < 2; ni++)
        #pragma unroll
        for (int jj = 0; jj < 4; jj++){
          const int grow = wr + mi*16 + lg*4 + jj;
          if (grow < 160){
            const float v = acc[mi][ni][jj] * inv_[grow];
            attnout[(size_t)(b*160 + grow)*512 + h*64 + wc + ni*16 + lr] = f2bf(v);
          }
        }
  }
}

// ---------- final: three images + per-block |err| partials; 4 pixels/thread ----------
__global__ __launch_bounds__(256) void finalize_k(const float* __restrict__ x, const int* __restrict__ slot,
                           const unsigned short* __restrict__ predb, const float* __restrict__ noise,
                           float* __restrict__ out, float* __restrict__ partial)
{
  const int i4 = blockIdx.x * 256 + threadIdx.x;
  const int idx = i4 * 4;
  const int w = idx % 224;
  const int h = (idx / 224) % 224;
  const int c = (idx / 50176) % 3;
  const int b = idx / 150528;
  const f32x4 xv = *(const f32x4*)(x + idx);
  const int p = (h >> 4) * 14 + (w >> 4);
  const int s = slot[b*196 + p];
  f32x4 rec = xv, noi = xv, mim = xv;
  float a = 0.0f;
  if (s >= 0){
    const int d = (h & 15)*48 + (w & 15)*3 + c;
    const size_t pb = (size_t)(b*160 + s)*768 + d;
    const size_t nb = (size_t)(b*147 + s)*768 + d;
    rec = f32x4{bf2f(predb[pb]), bf2f(predb[pb+3]), bf2f(predb[pb+6]), bf2f(predb[pb+9])};
    noi = f32x4{noise[nb], noise[nb+3], noise[nb+6], noise[nb+9]};
    mim = f32x4{1.0f, 1.0f, 1.0f, 1.0f};
    a = fabsf(rec[0] - xv[0]) + fabsf(rec[1] - xv[1]) + fabsf(rec[2] - xv[2]) + fabsf(rec[3] - xv[3]);
  }
  *(f32x4*)(out + idx) = rec;
  *(f32x4*)(out + 9633792 + idx) = noi;
  // mask_image starts at odd offset 19267585: shifted aligned store
  float prevm = __shfl_up(mim[3], 1);
  if ((threadIdx.x & 63) == 0 && idx > 0){
    const int pidx = idx - 1;
    const int pw2 = pidx % 224, ph2 = (pidx / 224) % 224;
    const int pb2 = pidx / 150528;
    const int pp = (ph2 >> 4) * 14 + (pw2 >> 4);
    prevm = (slot[pb2*196 + pp] >= 0) ? 1.0f : x[pidx];
  }
  *(f32x4*)(out + 19267584 + idx) = f32x4{prevm, mim[0], mim[1], mim[2]};
  if (i4 == 2408447) out[28901376] = mim[3];   // tail pixel
  // block reduce -> partial (no fence, no atomic — mse_reduce kernel provides visibility)
  #pragma unroll
  for (int o = 32; o > 0; o >>= 1) a += __shfl_down(a, o);
  __shared__ float wsum[4];
  if ((threadIdx.x & 63) == 0) wsum[threadIdx.x >> 6] = a;
  __syncthreads();
  if (threadIdx.x == 0)
    partial[blockIdx.x] = wsum[0] + wsum[1] + wsum[2] + wsum[3];
}

__global__ __launch_bounds__(1024) void mse_reduce(const float* __restrict__ partial, float* __restrict__ out){
  float a = 0.0f;
  for (int i = threadIdx.x; i < 9408; i += 1024) a += partial[i];
  #pragma unroll
  for (int o = 32; o > 0; o >>= 1) a += __shfl_down(a, o);
  __shared__ float wsum[16];
  if ((threadIdx.x & 63) == 0) wsum[threadIdx.x >> 6] = a;
  __syncthreads();
  if (threadIdx.x == 0){
    float s = 0.0f;
    #pragma unroll
    for (int i = 0; i < 16; i++) s += wsum[i];
    out[19267584] = s * (1.0f / 7225344.0f);
  }
}

// ---------- launch ----------
extern "C" void kernel_launch(void* const* d_in, const int* in_sizes, int n_in,
                              void* d_out, int out_size, void* d_ws, size_t ws_size,
                              hipStream_t stream)
{
  const float* x     = (const float*)d_in[0];
  const int*   shuf  = (const int*)d_in[1];
  const float* W_pe  = (const float*)d_in[2];
  const float* b_pe  = (const float*)d_in[3];
  const float* pos   = (const float*)d_in[4];
  const float* encW  = (const float*)d_in[5];
  const float* encB  = (const float*)d_in[6];
  const float* inW   = (const float*)d_in[7];
  const float* inB   = (const float*)d_in[8];
  const float* outW  = (const float*)d_in[9];
  const float* outB  = (const float*)d_in[10];
  const float* headW = (const float*)d_in[11];
  const float* headB = (const float*)d_in[12];
  const float* noise = (const float*)d_in[13];
  float* out = (float*)d_out;

  char* ws = (char*)d_ws;
  size_t cur = 0;
  auto alloc = [&](size_t bytes){ size_t o = cur; cur += (bytes + 255) & ~(size_t)255; return o; };

  int*   slot    = (int*)(ws + alloc(64*196*4));
  int*   invp    = (int*)(ws + alloc(64*196*4));
  int*   tokcat  = (int*)(ws + alloc(14336*4));
  float* partial = (float*)(ws + alloc(9408*4));
  unsigned short* wcat    = (unsigned short*)(ws + alloc((size_t)1441792*2));
  unsigned short* encw_b  = wcat;
  unsigned short* inw_b   = wcat +  262144;   // [Wq;Wk;Wv]
  unsigned short* headw_b = wcat + 1048576;   // [768][512]
  unsigned short* WpeT  = (unsigned short*)(ws + alloc((size_t)393216*2));  // [768][512]
  unsigned short* outwT = (unsigned short*)(ws + alloc((size_t)262144*2));  // [512][512]
  unsigned short* Wqpe  = (unsigned short*)(ws + alloc((size_t)393216*2));  // [512][768]
  unsigned short* Wepe  = (unsigned short*)(ws + alloc((size_t)393216*2));  // [512][768]
  unsigned short* Whp   = (unsigned short*)(ws + alloc((size_t)393216*2));  // [768][512]
  unsigned short* pe2b  = (unsigned short*)(ws + alloc((size_t)131072*2));  // [256][512]
  float* peq  = (float*)(ws + alloc((size_t)131072*4));
  float* pee  = (float*)(ws + alloc((size_t)131072*4));
  float* bh32 = (float*)(ws + alloc(768*4));
  unsigned short* maskA   = (unsigned short*)(ws + alloc((size_t)7864320*2));   // [10240][768]
  unsigned short* unmaskA = (unsigned short*)(ws + alloc((size_t)3145728*2));   // [4096][768]
  unsigned short* attnout = (unsigned short*)(ws + alloc((size_t)5242880*2));   // [10240][512]
  unsigned short* predb   = (unsigned short*)(ws + alloc((size_t)7864320*2));   // [10240][768]
  unsigned short* enc   = (unsigned short*)(ws + alloc((size_t)2097152*2));
  unsigned short* qb    = (unsigned short*)(ws + alloc((size_t)5242880*2));
  unsigned short* kvb   = (unsigned short*)(ws + alloc((size_t)4194304*2));

  prep_all<<<2237, 256, 0, stream>>>(shuf, slot, invp, W_pe, outW, WpeT, outwT,
                                     encW, inW, headW, wcat,
                                     pos, b_pe, outB, headB, pe2b, bh32);

  // fold GEMMs + patchify (one launch, 176 + 896 blocks)
  {
    GD t1 = { inw_b,  WpeT,   nullptr, nullptr, Wqpe,   nullptr, 768, 512, 4,   0, 12 };
    GD t2 = { encw_b, WpeT,   nullptr, nullptr, Wepe,   nullptr, 768, 512, 4,  48, 12 };
    GD t3 = { headw_b,outwT,  nullptr, nullptr, Whp,    nullptr, 512, 512, 4,  96,  8 };
    GD t4 = { pe2b,   inw_b,  inB,     nullptr, nullptr, peq,    512, 512, 3, 144,  8 };
    GD t5 = { pe2b,   encw_b, encB,    nullptr, nullptr, pee,    512, 512, 3, 160,  8 };
    fold_patch<<<1072, 256, 0, stream>>>(t1, t2, t3, t4, t5, x, invp, maskA, unmaskA, tokcat);
  }
  // q + enc (one launch, 896 blocks)
  {
    GD q  = { maskA,   Wqpe, peq, tokcat,         qb,  nullptr, 512, 768, 1,   0, 8 };
    GD en = { unmaskA, Wepe, pee, tokcat + 10240, enc, nullptr, 512, 768, 2, 640, 8 };
    gemm_two<<<896, 256, 0, stream>>>(q, en);
  }
  // kv = enc @ [Wk;Wv]^T + [bk;bv]
  {
    GD kv = { enc, inw_b + (size_t)512*512, inB + 512, nullptr, kvb, nullptr, 1024, 512, 0, 0, 16 };
    gemm_one<<<512, 256, 0, stream>>>(kv);
  }
  attn_mfma<<<512, 256, 0, stream>>>(qb, kvb, attnout);
  // pred = attn_raw @ Whp^T + bh
  {
    GD pr = { attnout, Whp, bh32, nullptr, predb, nullptr, 768, 512, 0, 0, 12 };
    gemm_one<<<960, 256, 0, stream>>>(pr);
  }

  finalize_k<<<9408, 256, 0, stream>>>(x, slot, predb, noise, out, partial);
  mse_reduce<<<1, 1024, 0, stream>>>(partial, out);
}

// Round 13
// 170.112 us; speedup vs baseline: 3.0344x; 1.0612x over previous
//
#include <hip/hip_runtime.h>
#include <math.h>

typedef __attribute__((ext_vector_type(8))) __bf16 bf16x8;
typedef __attribute__((ext_vector_type(8))) unsigned short u16x8;
typedef __attribute__((ext_vector_type(4))) unsigned short u16x4;
typedef __attribute__((ext_vector_type(4))) float f32x4;

typedef unsigned int as1_u32 __attribute__((address_space(1)));
typedef unsigned int as3_u32 __attribute__((address_space(3)));

// ---------- helpers ----------
__device__ __forceinline__ float bf2f(unsigned short h){
  return __uint_as_float(((unsigned int)h) << 16);
}
__device__ __forceinline__ unsigned short f2bf(float f){
  unsigned int u = __float_as_uint(f);
  unsigned int r = (u + 0x7FFFu + ((u >> 16) & 1u)) >> 16;  // RNE
  return (unsigned short)r;
}

#if __has_builtin(__builtin_amdgcn_global_load_lds)
#define HAVE_GLOAD_LDS 1
__device__ __forceinline__ void gload16(const void* g, void* l){
  __builtin_amdgcn_global_load_lds((const as1_u32*)(unsigned long long)g,
                                   (as3_u32*)l, 16, 0, 0);
}
#else
#define HAVE_GLOAD_LDS 0
#endif

// ---------- prep_all: scatter+invp | transpose | conv(x4) | pe2b(x4) | bh32 ----------
// ranges: [0,49) scatter  [49,689) transpose  [689,2097) conv4  [2097,2225) pe2b4  [2225,2237) bh32
__global__ __launch_bounds__(256) void prep_all(
    const int* __restrict__ shuf, int* __restrict__ slot, int* __restrict__ invp,
    const float* __restrict__ Wpe, const float* __restrict__ outw,
    unsigned short* __restrict__ WpeT, unsigned short* __restrict__ outwT,
    const float* __restrict__ encW, const float* __restrict__ inW,
    const float* __restrict__ headW, unsigned short* __restrict__ wcat,
    const float* __restrict__ pos, const float* __restrict__ b_pe,
    const float* __restrict__ outb, const float* __restrict__ headb,
    unsigned short* __restrict__ pe2b, float* __restrict__ bh32)
{
  const int bid = blockIdx.x, t = threadIdx.x;
  __shared__ float tile[32][33];
  if (bid < 49){                                   // scatter: slot + inverse perm
    const int i = bid*256 + t;
    if (i < 64*196){
      const int b = i / 196, j = i % 196;
      const int p = shuf[b*196 + j];
      slot[b*196 + p] = (j < 147) ? j : -1;
      invp[b*196 + p] = j;
    }
  } else if (bid < 689){                           // transpose W_pe -> WpeT, out_w -> outwT
    int b2 = bid - 49;
    const float* src; unsigned short* dst; int R, C, bx, by;
    if (b2 < 384){ src = Wpe;  dst = WpeT;  R = 512; C = 768; bx = b2 % 24; by = b2 / 24; }
    else { b2 -= 384; src = outw; dst = outwT; R = 512; C = 512; bx = b2 % 16; by = b2 / 16; }
    const int tx = t & 31, ty = t >> 5;
    #pragma unroll
    for (int i = 0; i < 4; i++)
      tile[ty + i*8][tx] = src[(size_t)(by*32 + ty + i*8)*C + bx*32 + tx];
    __syncthreads();
    #pragma unroll
    for (int i = 0; i < 4; i++)
      dst[(size_t)(bx*32 + ty + i*8)*R + by*32 + tx] = f2bf(tile[tx][ty + i*8]);
  } else if (bid < 2097){                          // conv x4: encW|inW|headW -> bf16 wcat
    const int i = ((bid - 689)*256 + t) * 4;       // < 1441792; boundaries %4==0
    f32x4 v;
    if      (i <  262144) v = *(const f32x4*)(encW + i);
    else if (i < 1048576) v = *(const f32x4*)(inW + (i - 262144));
    else                  v = *(const f32x4*)(headW + (i - 1048576));
    u16x4 o = { f2bf(v[0]), f2bf(v[1]), f2bf(v[2]), f2bf(v[3]) };
    *(u16x4*)(wcat + i) = o;
  } else if (bid < 2225){                          // pe2b x4: rows 0..195 = pos+b_pe, 196..255 = 0
    const int i = ((bid - 2097)*256 + t) * 4;      // < 131072; 100352 %4==0, 512%4==0
    u16x4 o = {0, 0, 0, 0};
    if (i < 100352){
      const f32x4 pv = *(const f32x4*)(pos + i);
      const f32x4 bv = *(const f32x4*)(b_pe + (i & 511));
      o = u16x4{ f2bf(pv[0]+bv[0]), f2bf(pv[1]+bv[1]), f2bf(pv[2]+bv[2]), f2bf(pv[3]+bv[3]) };
    }
    *(u16x4*)(pe2b + i) = o;
  } else {                                         // bh32 = headW@outb + headb
    const int r = (bid - 2225)*64 + (t >> 2);      // 0..767
    const int q4 = t & 3;
    float a = 0.0f;
    const float* hw = headW + (size_t)r*512 + q4*128;
    const float* ob = outb + q4*128;
    for (int e = 0; e < 128; e++) a += hw[e] * ob[e];
    a += __shfl_down(a, 2, 4);
    a += __shfl_down(a, 1, 4);
    if (q4 == 0) bh32[r] = a + headb[r];
  }
}

// ---------- descriptor GEMM core (R5-proven structure) ----------
struct GD {
  const unsigned short* A; const unsigned short* W; const float* aux;
  const int* tok; unsigned short* ob; float* of;
  int N, K, mode, blk0, nx;
};

__device__ __forceinline__ void gemm_core(const GD g, int local, unsigned char* smem){
  const int tn = (local % g.nx) * 64;
  const int tm = (local / g.nx) * 128;
  const int N = g.N, K = g.K;
  unsigned short* As = (unsigned short*)smem;                   // 2 * 128*32
  unsigned short* Bs = (unsigned short*)(smem + 2*128*32*2);    // 2 * 64*32
  const int t = threadIdx.x;
  const int wave = t >> 6, lane = t & 63;
  const int wr = (wave >> 1) * 64, wc = (wave & 1) * 32;
  const int lr = lane & 15, lg = lane >> 4;

  f32x4 acc[4][2] = {};
  const int nt = K >> 5;

#if HAVE_GLOAD_LDS
  const int srow = lane >> 2;
  const int scol = (lane & 3) * 8;
  const unsigned short* Ag = g.A + (size_t)(tm + wave*32 + srow) * K + scol;
  const unsigned short* Bg = g.W + (size_t)(tn + wave*16 + srow) * K + scol;
  const size_t rstepA = (size_t)16 * K;

  auto issue = [&](int tile_i, int slot_i){
    const int k0 = tile_i * 32;
    unsigned short* Al = As + slot_i*(128*32) + wave*(32*32);
    unsigned short* Bl = Bs + slot_i*(64*32)  + wave*(16*32);
    gload16(Ag + k0,          Al);
    gload16(Ag + k0 + rstepA, Al + 16*32);
    gload16(Bg + k0,          Bl);
  };

  issue(0, 0);
  __syncthreads();

  for (int tt = 0; tt < nt; ++tt){
    const int cur = tt & 1;
    if (tt + 1 < nt) issue(tt + 1, cur ^ 1);
    const unsigned short* Ab = As + cur*(128*32);
    const unsigned short* Bb = Bs + cur*(64*32);
    bf16x8 av[4], bv[2];
    #pragma unroll
    for (int mi = 0; mi < 4; mi++) av[mi] = *(const bf16x8*)&Ab[(wr + mi*16 + lr)*32 + lg*8];
    #pragma unroll
    for (int ni = 0; ni < 2; ni++) bv[ni] = *(const bf16x8*)&Bb[(wc + ni*16 + lr)*32 + lg*8];
    #pragma unroll
    for (int mi = 0; mi < 4; mi++)
      #pragma unroll
      for (int ni = 0; ni < 2; ni++)
        acc[mi][ni] = __builtin_amdgcn_mfma_f32_16x16x32_bf16(av[mi], bv[ni], acc[mi][ni], 0, 0, 0);
    __syncthreads();   // drains vmcnt(0): prefetched tile resident; LDS reads done
  }
#else
  unsigned short* As1 = (unsigned short*)smem;
  unsigned short* Bs1 = (unsigned short*)(smem + 128*32*2);
  const int r0 = t >> 2;
  const int c0 = (t & 3) * 8;
  for (int k0 = 0; k0 < K; k0 += 32){
    u16x8 ra0 = *(const u16x8*)(g.A + (size_t)(tm + r0) * K + k0 + c0);
    u16x8 rb0 = (r0 < 64) ? *(const u16x8*)(g.W + (size_t)(tn + r0) * K + k0 + c0) : u16x8{};
    __syncthreads();
    *(u16x8*)&As1[r0 * 32 + c0] = ra0;
    if (r0 < 64) *(u16x8*)&Bs1[r0 * 32 + c0] = rb0;
    __syncthreads();
    bf16x8 av[4], bv[2];
    #pragma unroll
    for (int mi = 0; mi < 4; mi++) av[mi] = *(const bf16x8*)&As1[(wr + mi*16 + lr)*32 + lg*8];
    #pragma unroll
    for (int ni = 0; ni < 2; ni++) bv[ni] = *(const bf16x8*)&Bs1[(wc + ni*16 + lr)*32 + lg*8];
    #pragma unroll
    for (int mi = 0; mi < 4; mi++)
      #pragma unroll
      for (int ni = 0; ni < 2; ni++)
        acc[mi][ni] = __builtin_amdgcn_mfma_f32_16x16x32_bf16(av[mi], bv[ni], acc[mi][ni], 0, 0, 0);
  }
#endif

  const int mode = g.mode;
  #pragma unroll
  for (int ni = 0; ni < 2; ni++){
    const int gcol = tn + wc + ni*16 + lr;
    const float bval = (mode == 0 || mode == 3) ? g.aux[gcol] : 0.0f;
    #pragma unroll
    for (int mi = 0; mi < 4; mi++){
      #pragma unroll
      for (int jj = 0; jj < 4; jj++){
        const int grow = tm + wr + mi*16 + lg*4 + jj;
        float v = acc[mi][ni][jj] + bval;
        if (mode == 1 || mode == 2) v += g.aux[(size_t)(g.tok[grow] & 255) * 512 + gcol];
        if (mode == 2){
          const float u = v;
          v = 0.5f * u * (1.0f + tanhf(0.7978845608f * (u + 0.044715f * u * u * u)));
        }
        if (mode == 3) g.of[(size_t)grow * N + gcol] = v;
        else           g.ob[(size_t)grow * N + gcol] = f2bf(v);
      }
    }
  }
}

// wrappers (24 KB LDS -> 6 blocks/CU)
__global__ __launch_bounds__(256) void gemm_one(GD g){
  __shared__ __align__(16) unsigned char smem[24576];
  gemm_core(g, blockIdx.x, smem);
}
__global__ __launch_bounds__(256) void gemm_two(GD a, GD b){
  __shared__ __align__(16) unsigned char smem[24576];
  GD g = (blockIdx.x >= b.blk0) ? b : a;
  gemm_core(g, blockIdx.x - g.blk0, smem);
}

// ---------- fold GEMMs + patchify-by-image, one launch ----------
// blocks [0,176): 5 fold GEMMs. blocks [176, 176+896): patchify, one per (b, gh).
__global__ __launch_bounds__(256) void fold_patch(GD g0, GD g1, GD g2, GD g3, GD g4,
    const float* __restrict__ x, const int* __restrict__ invp,
    unsigned short* __restrict__ maskA, unsigned short* __restrict__ unmaskA,
    int* __restrict__ tokcat)
{
  __shared__ __align__(16) unsigned char smem[24576];
  const int bid = blockIdx.x, t = threadIdx.x;
  if (bid < 176){
    GD g = g0;
    if (bid >= g1.blk0) g = g1;
    if (bid >= g2.blk0) g = g2;
    if (bid >= g3.blk0) g = g3;
    if (bid >= g4.blk0) g = g4;
    gemm_core(g, bid - g.blk0, smem);
    return;
  }
  // patchify: block per (b, gh); read 48 contiguous x rows, repack 14 patches
  const int blk = bid - 176;
  const int b = blk / 14, gh = blk % 14;
  unsigned short* ld = (unsigned short*)smem;   // [14][768] bf16
  for (int e = t; e < 2688; e += 256){          // 3*16*56 float4 loads
    const int w4 = e % 56, rest = e / 56;
    const int phi = rest & 15, c = rest >> 4;
    const f32x4 v4 = *(const f32x4*)(x + (size_t)b*150528 + c*50176
                                     + (size_t)(gh*16 + phi)*224 + w4*4);
    const int gw = w4 >> 2, part = w4 & 3;
    const int dbase = gw*768 + phi*48 + part*12 + c;
    ld[dbase]     = f2bf(v4[0]);
    ld[dbase + 3] = f2bf(v4[1]);
    ld[dbase + 6] = f2bf(v4[2]);
    ld[dbase + 9] = f2bf(v4[3]);
  }
  __syncthreads();
  for (int e = t; e < 1344; e += 256){          // 14 patches * 96 u16x8 stores
    const int gw = e / 96, elem8 = e % 96;
    const int p = gh*14 + gw;
    const int j = invp[b*196 + p];
    unsigned short* dst;
    int row;
    if (j < 147){ row = b*160 + j;        dst = maskA; }
    else        { row = b*64 + (j - 147); dst = unmaskA; }
    *(u16x8*)&dst[(size_t)row*768 + elem8*8] = *(const u16x8*)&ld[gw*768 + elem8*8];
    if (elem8 == 0) tokcat[(j < 147) ? (b*160 + j) : (10240 + b*64 + (j - 147))] = p;
  }
}

// ---------- MFMA attention: block per (b,h); pwt bf16; pa aliases qs ----------
__global__ __launch_bounds__(256) void attn_mfma(const unsigned short* __restrict__ qb,
                                                 const unsigned short* __restrict__ kv,
                                                 unsigned short* __restrict__ attnout)
{
  __shared__ __align__(16) unsigned char smem[72064];
  unsigned short* qs  = (unsigned short*)smem;            // [192][72], reused as pa
  unsigned short* ks  = (unsigned short*)(smem + 27648);  // [64][72]
  unsigned short* vsT = (unsigned short*)(smem + 36864);  // [64][72]
  unsigned short* pwt = (unsigned short*)(smem + 46080);  // [192][66] bf16 scores
  float* inv_ = (float*)(smem + 71424);                   // [160]
  const int b = blockIdx.x >> 3, h = blockIdx.x & 7;
  const int t = threadIdx.x;
  const int wave = t >> 6, lane = t & 63;
  const int wr = (wave >> 1) * 96, wc = (wave & 1) * 32;
  const int lr = lane & 15, lg = lane >> 4;

  for (int idx = t; idx < 192*8; idx += 256){
    const int i = idx >> 3, g = idx & 7;
    u16x8 v = {};
    if (i < 160) v = *(const u16x8*)(qb + (size_t)(b*160 + i)*512 + h*64 + g*8);
    *(u16x8*)&qs[i*72 + g*8] = v;
  }
  for (int idx = t; idx < 64*8; idx += 256){
    const int j = idx >> 3, g = idx & 7;
    const size_t base = (size_t)(b*64 + j)*1024 + h*64 + g*8;
    u16x8 k8 = *(const u16x8*)(kv + base);
    u16x8 v8 = *(const u16x8*)(kv + base + 512);
    *(u16x8*)&ks[j*72 + g*8] = k8;
    #pragma unroll
    for (int d = 0; d < 8; d++) vsT[(g*8 + d)*72 + j] = v8[d];
  }
  __syncthreads();

  // QK^T -> pwt (bf16, scaled)
  {
    f32x4 acc[6][2] = {};
    #pragma unroll
    for (int ksv = 0; ksv < 2; ksv++){
      const int kk = ksv*32;
      bf16x8 av[6], bv[2];
      #pragma unroll
      for (int mi = 0; mi < 6; mi++) av[mi] = *(const bf16x8*)&qs[(wr + mi*16 + lr)*72 + kk + lg*8];
      #pragma unroll
      for (int ni = 0; ni < 2; ni++) bv[ni] = *(const bf16x8*)&ks[(wc + ni*16 + lr)*72 + kk + lg*8];
      #pragma unroll
      for (int mi = 0; mi < 6; mi++)
        #pragma unroll
        for (int ni = 0; ni < 2; ni++)
          acc[mi][ni] = __builtin_amdgcn_mfma_f32_16x16x32_bf16(av[mi], bv[ni], acc[mi][ni], 0, 0, 0);
    }
    #pragma unroll
    for (int mi = 0; mi < 6; mi++)
      #pragma unroll
      for (int ni = 0; ni < 2; ni++)
        #pragma unroll
        for (int jj = 0; jj < 4; jj++)
          pwt[(wr + mi*16 + lg*4 + jj)*66 + wc + ni*16 + lr] = f2bf(acc[mi][ni][jj] * 0.125f);
  }
  __syncthreads();

  // softmax rows (mask j>=49); write pa (aliases qs — QK reads done)
  unsigned short* pa = qs;
  if (t < 147){
    float sc[49];
    float m = -1e30f;
    #pragma unroll 7
    for (int j = 0; j < 49; j++){ sc[j] = bf2f(pwt[t*66 + j]); m = fmaxf(m, sc[j]); }
    float sum = 0.0f;
    for (int j = 0; j < 49; j++){
      const float e = __expf(sc[j] - m);
      sum += e;
      pa[t*72 + j] = f2bf(e);
    }
    inv_[t] = 1.0f / sum;
    for (int j = 49; j < 64; j++) pa[t*72 + j] = 0;
  } else if (t < 192){
    for (int j = 0; j < 64; j++) pa[t*72 + j] = 0;
    if (t < 160) inv_[t] = 0.0f;
  }
  __syncthreads();

  // PV
  {
    f32x4 acc[6][2] = {};
    #pragma unroll
    for (int ksv = 0; ksv < 2; ksv++){
      const int kk = ksv*32;
      bf16x8 av[6], bv[2];
      #pragma unroll
      for (int mi = 0; mi < 6; mi++) av[mi] = *(const bf16x8*)&pa[(wr + mi*16 + lr)*72 + kk + lg*8];
      #pragma unroll
      for (int ni = 0; ni < 2; ni++) bv[ni] = *(const bf16x8*)&vsT[(wc + ni*16 + lr)*72 + kk + lg*8];
      #pragma unroll
      for (int mi = 0; mi < 6; mi++)
        #pragma unroll
        for (int ni = 0; ni < 2; ni++)
          acc[mi][ni] = __builtin_amdgcn_mfma_f32_16x16x32_bf16(av[mi], bv[ni], acc[mi][ni], 0, 0, 0);
    }
    #pragma unroll
    for (int mi = 0; mi < 6; mi++)
      #pragma unroll
      for (int ni = 0; ni < 2; ni++)
        #pragma unroll
        for (int jj = 0; jj < 4; jj++){
          const int grow = wr + mi*16 + lg*4 + jj;
          if (grow < 160){
            const float v = acc[mi][ni][jj] * inv_[grow];
            attnout[(size_t)(b*160 + grow)*512 + h*64 + wc + ni*16 + lr] = f2bf(v);
          }
        }
  }
}

// ---------- finalize: block per (b,gh) stripe; LDS-staged pred/noise; coalesced IO ----------
__global__ __launch_bounds__(512) void finalize_k(const float* __restrict__ x, const int* __restrict__ slot,
                           const unsigned short* __restrict__ predb, const float* __restrict__ noise,
                           float* __restrict__ out, float* __restrict__ partial)
{
  __shared__ int slot_s[14];
  __shared__ unsigned short pred_s[14*768];   // 21504 B
  __shared__ float noi_s[14*768];             // 43008 B
  __shared__ float wsum[8];
  const int blk = blockIdx.x;                 // < 896
  const int b = blk / 14, gh = blk % 14;
  const int t = threadIdx.x;

  if (t < 14) slot_s[t] = slot[b*196 + gh*14 + t];
  __syncthreads();
  // stage masked patches' pred rows (coalesced u16x8) and noise rows (coalesced f32x4)
  for (int e = t; e < 14*96; e += 512){
    const int gw = e / 96, k = e % 96;
    const int s = slot_s[gw];
    if (s >= 0)
      *(u16x8*)&pred_s[gw*768 + k*8] = *(const u16x8*)(predb + (size_t)(b*160 + s)*768 + k*8);
  }
  for (int e = t; e < 14*192; e += 512){
    const int gw = e / 192, k = e % 192;
    const int s = slot_s[gw];
    if (s >= 0)
      *(f32x4*)&noi_s[gw*768 + k*4] = *(const f32x4*)(noise + (size_t)(b*147 + s)*768 + k*4);
  }
  __syncthreads();

  float a = 0.0f;
  for (int e = t; e < 2688; e += 512){        // 3ch * 16rows * 56 quads
    const int w4 = e % 56, rest = e / 56;
    const int phi = rest & 15, c = rest >> 4;
    const int gw = w4 >> 2, part = w4 & 3;
    const int idx = b*150528 + c*50176 + (gh*16 + phi)*224 + w4*4;
    const f32x4 xv = *(const f32x4*)(x + idx);
    const int s = slot_s[gw];
    f32x4 rec = xv, noi = xv, mim = xv;
    if (s >= 0){
      const int dbase = gw*768 + phi*48 + part*12 + c;
      rec = f32x4{bf2f(pred_s[dbase]), bf2f(pred_s[dbase+3]), bf2f(pred_s[dbase+6]), bf2f(pred_s[dbase+9])};
      noi = f32x4{noi_s[dbase], noi_s[dbase+3], noi_s[dbase+6], noi_s[dbase+9]};
      mim = f32x4{1.0f, 1.0f, 1.0f, 1.0f};
      a += fabsf(rec[0]-xv[0]) + fabsf(rec[1]-xv[1]) + fabsf(rec[2]-xv[2]) + fabsf(rec[3]-xv[3]);
    }
    *(f32x4*)(out + idx) = rec;
    *(f32x4*)(out + 9633792 + idx) = noi;
    // mask_image at odd offset 19267585: shifted aligned store {mim[idx-1], mim[0..2]}
    float prevm = __shfl_up(mim[3], 1);
    if ((t & 63) == 0 || w4 == 0){
      const int pidx = idx - 1;
      if (pidx >= 0){
        const int w2 = pidx % 224, h2 = (pidx / 224) % 224;
        const int b2 = pidx / 150528;
        const int p2i = (h2 >> 4) * 14 + (w2 >> 4);
        prevm = (slot[b2*196 + p2i] >= 0) ? 1.0f : x[pidx];
      } else prevm = 0.0f;   // slot 19267584 = mse scalar, overwritten by mse_reduce
    }
    *(f32x4*)(out + 19267584 + idx) = f32x4{prevm, mim[0], mim[1], mim[2]};
    if (idx == 9633788) out[28901376] = mim[3];   // global last pixel
  }
  // block reduce -> partial
  #pragma unroll
  for (int o = 32; o > 0; o >>= 1) a += __shfl_down(a, o);
  if ((t & 63) == 0) wsum[t >> 6] = a;
  __syncthreads();
  if (t == 0){
    float s8 = 0.0f;
    #pragma unroll
    for (int i = 0; i < 8; i++) s8 += wsum[i];
    partial[blk] = s8;
  }
}

__global__ __launch_bounds__(896) void mse_reduce(const float* __restrict__ partial, float* __restrict__ out){
  float a = (threadIdx.x < 896) ? partial[threadIdx.x] : 0.0f;
  #pragma unroll
  for (int o = 32; o > 0; o >>= 1) a += __shfl_down(a, o);
  __shared__ float wsum[14];
  if ((threadIdx.x & 63) == 0) wsum[threadIdx.x >> 6] = a;
  __syncthreads();
  if (threadIdx.x == 0){
    float s = 0.0f;
    #pragma unroll
    for (int i = 0; i < 14; i++) s += wsum[i];
    out[19267584] = s * (1.0f / 7225344.0f);
  }
}

// ---------- launch ----------
extern "C" void kernel_launch(void* const* d_in, const int* in_sizes, int n_in,
                              void* d_out, int out_size, void* d_ws, size_t ws_size,
                              hipStream_t stream)
{
  const float* x     = (const float*)d_in[0];
  const int*   shuf  = (const int*)d_in[1];
  const float* W_pe  = (const float*)d_in[2];
  const float* b_pe  = (const float*)d_in[3];
  const float* pos   = (const float*)d_in[4];
  const float* encW  = (const float*)d_in[5];
  const float* encB  = (const float*)d_in[6];
  const float* inW   = (const float*)d_in[7];
  const float* inB   = (const float*)d_in[8];
  const float* outW  = (const float*)d_in[9];
  const float* outB  = (const float*)d_in[10];
  const float* headW = (const float*)d_in[11];
  const float* headB = (const float*)d_in[12];
  const float* noise = (const float*)d_in[13];
  float* out = (float*)d_out;

  char* ws = (char*)d_ws;
  size_t cur = 0;
  auto alloc = [&](size_t bytes){ size_t o = cur; cur += (bytes + 255) & ~(size_t)255; return o; };

  int*   slot    = (int*)(ws + alloc(64*196*4));
  int*   invp    = (int*)(ws + alloc(64*196*4));
  int*   tokcat  = (int*)(ws + alloc(14336*4));
  float* partial = (float*)(ws + alloc(896*4));
  unsigned short* wcat    = (unsigned short*)(ws + alloc((size_t)1441792*2));
  unsigned short* encw_b  = wcat;
  unsigned short* inw_b   = wcat +  262144;   // [Wq;Wk;Wv]
  unsigned short* headw_b = wcat + 1048576;   // [768][512]
  unsigned short* WpeT  = (unsigned short*)(ws + alloc((size_t)393216*2));  // [768][512]
  unsigned short* outwT = (unsigned short*)(ws + alloc((size_t)262144*2));  // [512][512]
  unsigned short* Wqpe  = (unsigned short*)(ws + alloc((size_t)393216*2));  // [512][768]
  unsigned short* Wepe  = (unsigned short*)(ws + alloc((size_t)393216*2));  // [512][768]
  unsigned short* Whp   = (unsigned short*)(ws + alloc((size_t)393216*2));  // [768][512]
  unsigned short* pe2b  = (unsigned short*)(ws + alloc((size_t)131072*2));  // [256][512]
  float* peq  = (float*)(ws + alloc((size_t)131072*4));
  float* pee  = (float*)(ws + alloc((size_t)131072*4));
  float* bh32 = (float*)(ws + alloc(768*4));
  unsigned short* maskA   = (unsigned short*)(ws + alloc((size_t)7864320*2));   // [10240][768]
  unsigned short* unmaskA = (unsigned short*)(ws + alloc((size_t)3145728*2));   // [4096][768]
  unsigned short* attnout = (unsigned short*)(ws + alloc((size_t)5242880*2));   // [10240][512]
  unsigned short* predb   = (unsigned short*)(ws + alloc((size_t)7864320*2));   // [10240][768]
  unsigned short* enc   = (unsigned short*)(ws + alloc((size_t)2097152*2));
  unsigned short* qb    = (unsigned short*)(ws + alloc((size_t)5242880*2));
  unsigned short* kvb   = (unsigned short*)(ws + alloc((size_t)4194304*2));

  prep_all<<<2237, 256, 0, stream>>>(shuf, slot, invp, W_pe, outW, WpeT, outwT,
                                     encW, inW, headW, wcat,
                                     pos, b_pe, outB, headB, pe2b, bh32);

  // fold GEMMs + patchify (one launch, 176 + 896 blocks)
  {
    GD t1 = { inw_b,  WpeT,   nullptr, nullptr, Wqpe,   nullptr, 768, 512, 4,   0, 12 };
    GD t2 = { encw_b, WpeT,   nullptr, nullptr, Wepe,   nullptr, 768, 512, 4,  48, 12 };
    GD t3 = { headw_b,outwT,  nullptr, nullptr, Whp,    nullptr, 512, 512, 4,  96,  8 };
    GD t4 = { pe2b,   inw_b,  inB,     nullptr, nullptr, peq,    512, 512, 3, 144,  8 };
    GD t5 = { pe2b,   encw_b, encB,    nullptr, nullptr, pee,    512, 512, 3, 160,  8 };
    fold_patch<<<1072, 256, 0, stream>>>(t1, t2, t3, t4, t5, x, invp, maskA, unmaskA, tokcat);
  }
  // q + enc (one launch, 896 blocks)
  {
    GD q  = { maskA,   Wqpe, peq, tokcat,         qb,  nullptr, 512, 768, 1,   0, 8 };
    GD en = { unmaskA, Wepe, pee, tokcat + 10240, enc, nullptr, 512, 768, 2, 640, 8 };
    gemm_two<<<896, 256, 0, stream>>>(q, en);
  }
  // kv = enc @ [Wk;Wv]^T + [bk;bv]
  {
    GD kv = { enc, inw_b + (size_t)512*512, inB + 512, nullptr, kvb, nullptr, 1024, 512, 0, 0, 16 };
    gemm_one<<<512, 256, 0, stream>>>(kv);
  }
  attn_mfma<<<512, 256, 0, stream>>>(qb, kvb, attnout);
  // pred = attn_raw @ Whp^T + bh
  {
    GD pr = { attnout, Whp, bh32, nullptr, predb, nullptr, 768, 512, 0, 0, 12 };
    gemm_one<<<960, 256, 0, stream>>>(pr);
  }

  finalize_k<<<896, 512, 0, stream>>>(x, slot, predb, noise, out, partial);
  mse_reduce<<<1, 896, 0, stream>>>(partial, out);
}